// Round 9
// baseline (245.902 us; speedup 1.0000x reference)
//
#include <hip/hip_runtime.h>
#include <hip/hip_bf16.h>

#define S_LEN 2048
#define D_DIM 1024
#define NBATCH 4

typedef __attribute__((ext_vector_type(4)))  float f32x4;
typedef __attribute__((ext_vector_type(8)))  short s16x8;   // MFMA bf16 operand
typedef __attribute__((ext_vector_type(4)))  unsigned short u16x4;

__device__ __forceinline__ unsigned short f2b(float f) {
    __hip_bfloat16 h = __float2bfloat16(f);
    return __builtin_bit_cast(unsigned short, h);
}

// Direct global->LDS DMA, 16 bytes per lane. LDS dest: wave-uniform base + lane*16.
__device__ __forceinline__ void load_lds16(const unsigned short* g, unsigned short* l) {
    __builtin_amdgcn_global_load_lds(
        (const __attribute__((address_space(1))) void*)(g),
        (__attribute__((address_space(3))) void*)(l), 16, 0, 0);
}

// ---------------------------------------------------------------------------
__global__ __launch_bounds__(256)
void cvt_kernel(const float* __restrict__ in, unsigned short* __restrict__ out) {
    long i = ((long)blockIdx.x * 256 + threadIdx.x) * 4;
    f32x4 v = *(const f32x4*)(in + i);
    u16x4 o;
    o.x = f2b(v.x); o.y = f2b(v.y); o.z = f2b(v.z); o.w = f2b(v.w);
    *(u16x4*)(out + i) = o;
}

// ---------------------------------------------------------------------------
__global__ __launch_bounds__(256)
void transW_kernel(const float* __restrict__ W0, const float* __restrict__ W1,
                   const float* __restrict__ W2, unsigned short* __restrict__ WT) {
    const float* W = (blockIdx.z == 0) ? W0 : (blockIdx.z == 1) ? W1 : W2;
    unsigned short* O = WT + (long)blockIdx.z * 1024 * 1024;
    __shared__ float t[32][33];
    int tid = threadIdx.x;
    int r  = tid >> 3;
    int c4 = tid & 7;
    int bi = blockIdx.x, bj = blockIdx.y;
    f32x4 v = *(const f32x4*)&W[(long)(bi * 32 + r) * 1024 + bj * 32 + c4 * 4];
    t[r][c4 * 4 + 0] = v.x; t[r][c4 * 4 + 1] = v.y;
    t[r][c4 * 4 + 2] = v.z; t[r][c4 * 4 + 3] = v.w;
    __syncthreads();
    u16x4 o;
    o.x = f2b(t[c4 * 4 + 0][r]); o.y = f2b(t[c4 * 4 + 1][r]);
    o.z = f2b(t[c4 * 4 + 2][r]); o.w = f2b(t[c4 * 4 + 3][r]);
    *(u16x4*)&O[(long)(bj * 32 + r) * 1024 + bi * 32 + c4 * 4] = o;
}

// ---------------------------------------------------------------------------
// Counted-vmcnt triple-buffered GEMM: C[m][n] = alpha * sum_k A[m][k]*Bt[n][k]
// Fixed 128x256 tile, BK=64, 512 threads = 8 waves (2M x 4N), 64x64 out/wave.
// LDS: 3 buffers x (128+256)*64 shorts = 144 KiB. Stage via global_load_lds w=16,
// 6 loads/thread/tile. Pipeline keeps 2 tiles in flight:
//   prologue: stage(0); stage(1)
//   iter t:   s_waitcnt vmcnt(6)   [stage(t) done; stage(t+1) still flying]
//             s_barrier            [all waves' stage(t) visible]
//             stage(t+2)           [async; overwrites buf read at iter t-1 — safe:
//                                   those reads are register-resident pre-barrier]
//             ds_read(t); setprio(1); 32 MFMA; setprio(0)
// vmcnt never drains to 0 in the main loop (T4). T2 XOR swizzle: global source
// granule pre-swizzled (g ^ row&7), linear LDS dest, same XOR on ds_read.
// OMODE: 0 = bf16 out, 1 = f32 out.
// CSKIP: causal block skip (scores): 2*bn > bm -> exit.  (bm reversed: big-first)
// CKLIM: causal K limit (PV): kend = (bm+1)*128.         (bm reversed: big-first)
template<int OMODE, bool CSKIP, bool CKLIM>
__global__ __launch_bounds__(512, 2)
void gemm_cnt(const unsigned short* __restrict__ A, int lda, long aStride,
              const unsigned short* __restrict__ Bt, int ldb, long bStride,
              void* __restrict__ Cv, int ldc, long cStride,
              int K, float alpha) {
    constexpr int BUF = (128 + 256) * 64;          // shorts per buffer
    const int bm = (CSKIP || CKLIM) ? (gridDim.x - 1 - blockIdx.x) : blockIdx.x;
    const int bn = blockIdx.y, bz = blockIdx.z;
    if (CSKIP && 2 * bn > bm) return;
    A  += (long)bz * aStride;
    Bt += (long)bz * bStride;

    const int tid  = threadIdx.x;
    const int lane = tid & 63;
    const int wid  = tid >> 6;          // 0..7
    const int wm   = wid >> 2;          // 0..1  (64-row slab)
    const int wn   = wid & 3;           // 0..3  (64-col slab)

    extern __shared__ __align__(16) unsigned short smem[];   // 3 * BUF shorts

    f32x4 acc[4][4] = {};

    const int kend = CKLIM ? (bm + 1) * 128 : K;
    const int nt   = kend / 64;                    // >= 2 for all our launches

    // staging: thread -> row srl (per 64-row slice), pre-swizzled granule sg
    const int srl = tid >> 3;
    const int sg  = (tid & 7) ^ (srl & 7);
    const unsigned short* agb = A  + (long)(bm * 128 + srl) * lda + sg * 8;
    const unsigned short* bgb = Bt + (long)(bn * 256 + srl) * ldb + sg * 8;

    // fragment map
    const int fr   = lane & 15;
    const int fg   = lane >> 4;
    const int rxor = (fr & 7) * 8;     // ds_read swizzle (shorts)

    auto stage = [&](int t) {
        const int k0 = t * 64;
        unsigned short* d = smem + (t % 3) * BUF;
        #pragma unroll
        for (int i = 0; i < 2; ++i)
            load_lds16(agb + (long)(i * 64) * lda + k0, d + i * 4096 + tid * 8);
        #pragma unroll
        for (int i = 0; i < 4; ++i)
            load_lds16(bgb + (long)(i * 64) * ldb + k0, d + 8192 + i * 4096 + tid * 8);
    };

    stage(0);
    stage(1);

    for (int t = 0; t < nt; ++t) {
        if (t + 1 < nt) asm volatile("s_waitcnt vmcnt(6)" ::: "memory");
        else            asm volatile("s_waitcnt vmcnt(0)" ::: "memory");
        __builtin_amdgcn_s_barrier();
        if (t + 2 < nt) stage(t + 2);

        const unsigned short* as = smem + (t % 3) * BUF;
        const unsigned short* bs = as + 8192;
        #pragma unroll
        for (int ks = 0; ks < 2; ++ks) {
            s16x8 af[4], bf[4];
            #pragma unroll
            for (int m = 0; m < 4; ++m) {
                const int row = wm * 64 + m * 16 + fr;
                af[m] = *(const s16x8*)&as[row * 64 + (((ks * 4 + fg) * 8) ^ rxor)];
            }
            #pragma unroll
            for (int n = 0; n < 4; ++n) {
                const int row = wn * 64 + n * 16 + fr;
                bf[n] = *(const s16x8*)&bs[row * 64 + (((ks * 4 + fg) * 8) ^ rxor)];
            }
            __builtin_amdgcn_s_setprio(1);
            #pragma unroll
            for (int m = 0; m < 4; ++m)
                #pragma unroll
                for (int n = 0; n < 4; ++n)
                    acc[m][n] = __builtin_amdgcn_mfma_f32_16x16x32_bf16(af[m], bf[n], acc[m][n], 0, 0, 0);
            __builtin_amdgcn_s_setprio(0);
        }
    }

    // epilogue: C/D layout col = lane&15, row = (lane>>4)*4 + reg
    const int crow0 = bm * 128 + wm * 64;
    const int ccol0 = bn * 256 + wn * 64;
    const int cr = (lane >> 4) * 4;
    const int cc = lane & 15;
    if (OMODE == 0) {
        unsigned short* C = (unsigned short*)Cv + (long)bz * cStride;
        #pragma unroll
        for (int m = 0; m < 4; ++m)
            #pragma unroll
            for (int r = 0; r < 4; ++r) {
                const long row = crow0 + m * 16 + cr + r;
                #pragma unroll
                for (int n = 0; n < 4; ++n)
                    C[row * ldc + ccol0 + n * 16 + cc] = f2b(acc[m][n][r] * alpha);
            }
    } else {
        float* C = (float*)Cv + (long)bz * cStride;
        #pragma unroll
        for (int m = 0; m < 4; ++m)
            #pragma unroll
            for (int r = 0; r < 4; ++r) {
                const long row = crow0 + m * 16 + cr + r;
                #pragma unroll
                for (int n = 0; n < 4; ++n)
                    C[row * ldc + ccol0 + n * 16 + cc] = acc[m][n][r] * alpha;
            }
    }
}

// ---------------------------------------------------------------------------
// Causal row softmax, in-place fp32 scores row -> bf16 P row (zero-filled past i).
__global__ __launch_bounds__(256)
void softmax_rows(float* __restrict__ scores) {
    const int i = blockIdx.x;
    const int z = blockIdx.y;
    float* row = scores + ((long)z * S_LEN + i) * S_LEN;
    const int c = i + 1;
    const int tid  = threadIdx.x;
    const int lane = tid & 63;
    const int wid  = tid >> 6;

    f32x4 v0 = ((const f32x4*)row)[tid];
    f32x4 v1 = ((const f32x4*)row)[tid + 256];
    const int j0 = tid * 4, j1 = (tid + 256) * 4;

    float m = -3.4e38f;
    #pragma unroll
    for (int e = 0; e < 4; e++) {
        if (j0 + e < c) m = fmaxf(m, v0[e]);
        if (j1 + e < c) m = fmaxf(m, v1[e]);
    }
    #pragma unroll
    for (int off = 32; off > 0; off >>= 1) m = fmaxf(m, __shfl_xor(m, off));
    __shared__ float redm[4];
    if (lane == 0) redm[wid] = m;
    __syncthreads();
    m = fmaxf(fmaxf(redm[0], redm[1]), fmaxf(redm[2], redm[3]));

    float e0[4], e1[4];
    float s = 0.f;
    #pragma unroll
    for (int e = 0; e < 4; e++) {
        e0[e] = (j0 + e < c) ? __expf(v0[e] - m) : 0.f;
        e1[e] = (j1 + e < c) ? __expf(v1[e] - m) : 0.f;
        s += e0[e] + e1[e];
    }
    #pragma unroll
    for (int off = 32; off > 0; off >>= 1) s += __shfl_xor(s, off);
    __shared__ float reds[4];
    if (lane == 0) reds[wid] = s;
    __syncthreads();   // loads retired before in-place writes
    s = reds[0] + reds[1] + reds[2] + reds[3];
    const float rinv = 1.f / s;

    unsigned short* P = (unsigned short*)row;
    u16x4 o0, o1;
    o0.x = f2b(e0[0] * rinv); o0.y = f2b(e0[1] * rinv);
    o0.z = f2b(e0[2] * rinv); o0.w = f2b(e0[3] * rinv);
    o1.x = f2b(e1[0] * rinv); o1.y = f2b(e1[1] * rinv);
    o1.z = f2b(e1[2] * rinv); o1.w = f2b(e1[3] * rinv);
    *(u16x4*)&P[j0] = o0;
    *(u16x4*)&P[j1] = o1;
}

// ---------------------------------------------------------------------------
extern "C" void kernel_launch(void* const* d_in, const int* in_sizes, int n_in,
                              void* d_out, int out_size, void* d_ws, size_t ws_size,
                              hipStream_t stream) {
    const float* x  = (const float*)d_in[0];
    const float* Wq = (const float*)d_in[1];
    const float* Wk = (const float*)d_in[2];
    const float* Wv = (const float*)d_in[3];
    float* out = (float*)d_out;
    char* ws = (char*)d_ws;
    const size_t MiB = 1ull << 20;

    unsigned short* xb  = (unsigned short*)(ws);              // [8192][1024] bf16
    unsigned short* WT  = (unsigned short*)(ws + 16 * MiB);   // 3x [1024][1024] bf16
    unsigned short* Qb  = (unsigned short*)(ws + 22 * MiB);   // [4][2048][1024]
    unsigned short* Kb  = (unsigned short*)(ws + 38 * MiB);   // [4][2048][1024]
    unsigned short* VbT = (unsigned short*)(ws + 54 * MiB);   // [1024][8192]
    float* scores       = (float*)(ws + 70 * MiB);            // nb x [2048][2048] fp32

    int nb;
    if      (ws_size >= (70 + 64) * MiB) nb = 4;
    else if (ws_size >= (70 + 32) * MiB) nb = 2;
    else                                 nb = 1;

    // 144 KiB dynamic LDS (3 buffers x 48 KiB) — opt-in above 64 KiB
    const int LDS = 3 * (128 + 256) * 64 * 2;
    hipFuncSetAttribute((const void*)gemm_cnt<0,false,false>,
                        hipFuncAttributeMaxDynamicSharedMemorySize, LDS);
    hipFuncSetAttribute((const void*)gemm_cnt<1,true,false>,
                        hipFuncAttributeMaxDynamicSharedMemorySize, LDS);
    hipFuncSetAttribute((const void*)gemm_cnt<1,false,true>,
                        hipFuncAttributeMaxDynamicSharedMemorySize, LDS);

    // 1) converts
    cvt_kernel<<<8192, 256, 0, stream>>>(x, xb);
    transW_kernel<<<dim3(32, 32, 3), 256, 0, stream>>>(Wq, Wk, Wv, WT);

    // 2) projections
    // Q,K = x*W : 128x256 tiles, z picks {Wq->Qb, Wk->Kb}
    gemm_cnt<0,false,false><<<dim3(64, 4, 2), 512, LDS, stream>>>(
        xb, 1024, 0L, WT, 1024, (long)1024 * 1024,
        Qb, 1024, (long)8192 * 1024, 1024, 1.0f);
    // V^T = Wv^T * x^T -> [1024][8192]
    gemm_cnt<0,false,false><<<dim3(8, 32, 1), 512, LDS, stream>>>(
        WT + (long)2 * 1024 * 1024, 1024, 0L, xb, 1024, 0L,
        VbT, 8192, 0L, 1024, 1.0f);

    // 3) attention, chunked over batches
    const float alpha = 0.03125f;   // 1/sqrt(1024)
    for (int b0 = 0; b0 < NBATCH; b0 += nb) {
        const int nz = (NBATCH - b0 < nb) ? (NBATCH - b0) : nb;
        // scores = Q K^T * alpha  (causal 128x256-block skip, big-bm-first)
        gemm_cnt<1,true,false><<<dim3(16, 8, nz), 512, LDS, stream>>>(
            Qb + (long)b0 * S_LEN * D_DIM, 1024, (long)S_LEN * D_DIM,
            Kb + (long)b0 * S_LEN * D_DIM, 1024, (long)S_LEN * D_DIM,
            scores, S_LEN, (long)S_LEN * S_LEN, 1024, alpha);
        // softmax rows (in-place bf16 P, zero-filled past diagonal)
        softmax_rows<<<dim3(S_LEN, nz), 256, 0, stream>>>(scores);
        // O = P V  (K limited per 128-row block, big-K-first; P at bf16 stride 4096)
        gemm_cnt<1,false,true><<<dim3(16, 4, nz), 512, LDS, stream>>>(
            (const unsigned short*)scores, 2 * S_LEN, 2L * S_LEN * S_LEN,
            VbT + (long)b0 * S_LEN, 8192, (long)S_LEN,
            out + (long)b0 * S_LEN * D_DIM, 1024, (long)S_LEN * D_DIM,
            S_LEN, 1.0f);
    }
}